// Round 4
// baseline (502.761 us; speedup 1.0000x reference)
//
#include <hip/hip_runtime.h>
#include <hip/hip_bf16.h>
#include <math.h>

#define BB 4
#define QQ 75
#define NBQ 300        // BB*QQ
#define CC 640
#define HW 121
#define NW 5
#define KS 5
#define SS 25          // NW*KS
#define MS 605         // KS*HW
#define JT 3025        // NW*MS
#define JSPLIT 384     // h=0: j in [0,384) (3 tiles), h=1: [384,605) (2 tiles)
#define NPART 10       // NW * 2 halves

typedef __attribute__((ext_vector_type(8))) short short8;
typedef __attribute__((ext_vector_type(4))) float f32x4;

// workspace float offsets
#define OFF_SBF   0
#define SBF_F     (BB*JT*CC/2)            // 3,872,000 floats (bf16 storage)
#define OFF_QBF   (OFF_SBF + SBF_F)
#define QBF_F     (NBQ*HW*CC/2)           // 11,616,000 floats
#define OFF_P     (OFF_QBF + QBF_F)       // float4 partials [300][10][121]
#define P_F       (NBQ*NPART*HW*4)        // 1,452,000 floats
#define OFF_LOSS  (OFF_P + P_F)

__device__ __forceinline__ void async16(const void* g, void* l) {
    __builtin_amdgcn_global_load_lds(
        (const __attribute__((address_space(1))) unsigned int*)g,
        (__attribute__((address_space(3))) unsigned int*)l, 16, 0, 0);
}

// ---------------------------------------------------------------------------
// Fused: norm (pass 1, HBM-stream) + normalize/cast/transpose (pass 2, L2-hot).
// One block per descriptor column. Output [col][hw][c] bf16.
__global__ void prep_kernel(const float* __restrict__ sup, const float* __restrict__ qry,
                            __hip_bfloat16* __restrict__ Sbf, __hip_bfloat16* __restrict__ Qbf)
{
    const int col = blockIdx.x;      // 0..399
    const int t   = threadIdx.x;     // 256
    const float* src;
    __hip_bfloat16* dst;
    if (col < BB * SS) {
        const int b = col / SS, s = col % SS;
        const int n = s / KS, k = s % KS;
        src = sup + (size_t)col * (CC * HW);
        dst = Sbf + ((size_t)b * JT + n * MS + k * HW) * CC;
    } else {
        const int bq = col - BB * SS;
        src = qry + (size_t)bq * (CC * HW);
        dst = Qbf + (size_t)bq * (HW * CC);
    }

    __shared__ float inv[128];
    __shared__ float T[32][128];

    // ---- phase 1: sum of squares per hw (2 c-interleaved partials) ----
    const int cc2 = t >> 7, hw1 = t & 127;
    float ss = 0.f;
    if (hw1 < HW) {
        const float* p = src + hw1;
#pragma unroll 8
        for (int c = cc2; c < CC; c += 2) { float v = p[(size_t)c * HW]; ss = fmaf(v, v, ss); }
    }
    T[cc2][hw1] = ss;
    __syncthreads();
    if (t < 128) inv[t] = (t < HW) ? 1.f / (sqrtf(T[0][t] + T[1][t]) + 1e-8f) : 0.f;

    // ---- phase 2: scale + transpose + bf16 write (reads are cache-hot) ----
    for (int c0 = 0; c0 < CC; c0 += 32) {
        __syncthreads();
#pragma unroll
        for (int i = 0; i < 16; ++i) {
            int idx = t + i * 256;
            int cc = idx >> 7, hw = idx & 127;
            if (hw < HW) T[cc][hw] = src[(size_t)(c0 + cc) * HW + hw] * inv[hw];
        }
        __syncthreads();
        const int hw = t >> 1, half = t & 1;
        if (hw < HW) {
            __hip_bfloat16 hv[16];
#pragma unroll
            for (int i = 0; i < 16; ++i) hv[i] = __float2bfloat16(T[half * 16 + i][hw]);
            int4* op = reinterpret_cast<int4*>(dst + (size_t)hw * CC + c0 + half * 16);
            op[0] = reinterpret_cast<int4*>(hv)[0];
            op[1] = reinterpret_cast<int4*>(hv)[1];
        }
    }
}

// ---------------------------------------------------------------------------
// Per (bq, n, half): MFMA cosine GEMM over a j-range with register-resident
// top3/argmax. Partial out: float4 {t0,t1,t2,arg}.
__launch_bounds__(256, 2)
__global__ void simi_kernel(const __hip_bfloat16* __restrict__ Sbf,
                            const __hip_bfloat16* __restrict__ Qbf,
                            float4* __restrict__ pout)
{
    const int bq  = blockIdx.x;
    const int y   = blockIdx.y;            // n*2 + h
    const int n   = y >> 1, h = y & 1;
    const int b   = bq / QQ;
    const int ms_lo = h ? JSPLIT : 0;
    const int ms_hi = h ? MS : JSPLIT;
    const int tid = threadIdx.x;
    const int lane = tid & 63, wid = tid >> 6;
    const int l15 = lane & 15, l4 = lane >> 4;
    const int wr0 = (wid & 1) * 64;    // wave row base
    const int wc0 = (wid >> 1) * 64;   // wave col base (tile-local)

    const unsigned short* qbase = (const unsigned short*)(Qbf + (size_t)bq * (HW * CC));
    const unsigned short* sbase = (const unsigned short*)(Sbf + ((size_t)b * JT + n * MS) * CC);

    __shared__ __align__(16) unsigned short AsBuf[128 * 64];  // 16 KB, xor-swizzled
    __shared__ __align__(16) unsigned short BsBuf[128 * 64];  // 16 KB
    __shared__ float4 mbuf[128];                              // 2 KB cross-wave merge

    const int srow = lane >> 3;              // row within 8-row segment
    const int kb   = (lane & 7) ^ srow;      // swizzled k-block held by this lane
    int aoff[4];
#pragma unroll
    for (int p = 0; p < 4; ++p) {
        int arow = wid * 32 + p * 8 + srow;
        int grow = arow < HW ? arow : HW - 1;
        aoff[p] = grow * CC + kb * 8;
    }

    float rt0[16], rt1[16], rt2[16]; int ra[16];
#pragma unroll
    for (int i = 0; i < 16; ++i) { rt0[i] = -INFINITY; rt1[i] = -INFINITY; rt2[i] = -INFINITY; ra[i] = 0; }

    for (int ms0 = ms_lo; ms0 < ms_hi; ms0 += 128) {
        int boff[4];
#pragma unroll
        for (int p = 0; p < 4; ++p) {
            int j = ms0 + wid * 32 + p * 8 + srow;
            int jc = j < ms_hi ? j : ms_hi - 1;
            boff[p] = jc * CC + kb * 8;
        }

        f32x4 acc[4][4];
#pragma unroll
        for (int mi = 0; mi < 4; ++mi)
#pragma unroll
            for (int ni = 0; ni < 4; ++ni)
#pragma unroll
                for (int r = 0; r < 4; ++r) acc[mi][ni][r] = 0.f;

        for (int c0 = 0; c0 < CC; c0 += 64) {
            __syncthreads();
#pragma unroll
            for (int p = 0; p < 4; ++p) {
                const int ldso = (wid * 4 + p) * 1024 + lane * 16;
                async16(qbase + aoff[p] + c0, (char*)AsBuf + ldso);
                async16(sbase + boff[p] + c0, (char*)BsBuf + ldso);
            }
            __syncthreads();
#pragma unroll
            for (int ks = 0; ks < 2; ++ks) {
                const int slot = (ks * 4 + l4) ^ (l15 & 7);
                short8 af[4], bf[4];
#pragma unroll
                for (int mi = 0; mi < 4; ++mi)
                    af[mi] = *(const short8*)(AsBuf + (wr0 + mi * 16 + l15) * 64 + slot * 8);
#pragma unroll
                for (int ni = 0; ni < 4; ++ni)
                    bf[ni] = *(const short8*)(BsBuf + (wc0 + ni * 16 + l15) * 64 + slot * 8);
#pragma unroll
                for (int mi = 0; mi < 4; ++mi)
#pragma unroll
                    for (int ni = 0; ni < 4; ++ni)
                        acc[mi][ni] = __builtin_amdgcn_mfma_f32_16x16x32_bf16(
                            af[mi], bf[ni], acc[mi][ni], 0, 0, 0);
            }
        }

        // in-register epilogue: ascending j keeps first-max tie rule
        int jg[4]; bool jvalid[4];
#pragma unroll
        for (int nf = 0; nf < 4; ++nf) {
            const int jl = ms0 + wc0 + nf * 16 + l15;
            jvalid[nf] = (jl < ms_hi);
            jg[nf] = n * MS + jl;
        }
#pragma unroll
        for (int mi = 0; mi < 4; ++mi)
#pragma unroll
            for (int nf = 0; nf < 4; ++nf)
#pragma unroll
                for (int r = 0; r < 4; ++r) {
                    const int si = mi * 4 + r;
                    float v = jvalid[nf] ? acc[mi][nf][r] : -INFINITY;
                    const bool gt = v > rt0[si];
                    ra[si] = gt ? jg[nf] : ra[si];
                    const float m1 = fminf(rt0[si], v);
                    rt0[si] = fmaxf(rt0[si], v);
                    const float m2 = fminf(rt1[si], m1);
                    rt1[si] = fmaxf(rt1[si], m1);
                    rt2[si] = fmaxf(rt2[si], m2);
                }
    }

    // butterfly merge across the 16 lanes of each col-group (masks 1,2,4,8)
#pragma unroll
    for (int si = 0; si < 16; ++si) {
#pragma unroll
        for (int mask = 1; mask <= 8; mask <<= 1) {
            const float o0 = __shfl_xor(rt0[si], mask);
            const float o1 = __shfl_xor(rt1[si], mask);
            const float o2 = __shfl_xor(rt2[si], mask);
            const int   oa = __shfl_xor(ra[si],  mask);
            const bool take = (o0 > rt0[si]) || (o0 == rt0[si] && oa < ra[si]);
            ra[si] = take ? oa : ra[si];
            float m1 = fminf(rt0[si], o0); rt0[si] = fmaxf(rt0[si], o0);
            float m2 = fminf(rt1[si], m1); rt1[si] = fmaxf(rt1[si], m1);
            rt2[si] = fmaxf(rt2[si], m2);
            m1 = fminf(rt0[si], o1); rt0[si] = fmaxf(rt0[si], o1);
            m2 = fminf(rt1[si], m1); rt1[si] = fmaxf(rt1[si], m1);
            rt2[si] = fmaxf(rt2[si], m2);
            m1 = fminf(rt0[si], o2); rt0[si] = fmaxf(rt0[si], o2);
            m2 = fminf(rt1[si], m1); rt1[si] = fmaxf(rt1[si], m1);
            rt2[si] = fmaxf(rt2[si], m2);
        }
    }

    // select this lane's slot (si == l15)
    float s0 = rt0[0], s1 = rt1[0], s2 = rt2[0]; int sa = ra[0];
#pragma unroll
    for (int i = 1; i < 16; ++i) {
        const bool p = (l15 == i);
        s0 = p ? rt0[i] : s0; s1 = p ? rt1[i] : s1; s2 = p ? rt2[i] : s2; sa = p ? ra[i] : sa;
    }
    const int m = wr0 + (l15 >> 2) * 16 + l4 * 4 + (l15 & 3);

    if ((wid >> 1) == 0) {
        float4 v; v.x = s0; v.y = s1; v.z = s2; v.w = __int_as_float(sa);
        mbuf[m] = v;
    }
    __syncthreads();
    if ((wid >> 1) == 1) {
        const float4 o = mbuf[m];
        const int oa = __float_as_int(o.w);
        const bool take = (o.x > s0) || (o.x == s0 && oa < sa);
        sa = take ? oa : sa;
        float m1 = fminf(s0, o.x); s0 = fmaxf(s0, o.x);
        float m2 = fminf(s1, m1);  s1 = fmaxf(s1, m1);
        s2 = fmaxf(s2, m2);
        m1 = fminf(s0, o.y); s0 = fmaxf(s0, o.y);
        m2 = fminf(s1, m1);  s1 = fmaxf(s1, m1);
        s2 = fmaxf(s2, m2);
        m1 = fminf(s0, o.z); s0 = fmaxf(s0, o.z);
        m2 = fminf(s1, m1);  s1 = fmaxf(s1, m1);
        s2 = fmaxf(s2, m2);
        if (m < HW) {
            float4 v; v.x = s0; v.y = s1; v.z = s2; v.w = __int_as_float(sa);
            pout[(bq * NPART + y) * HW + m] = v;
        }
    }
}

// ---------------------------------------------------------------------------
// Merge 10 partials (ascending j order), mutual-NN mask, logits, per-query CE.
__global__ void merge_kernel(const float4* __restrict__ pout, const int* __restrict__ qy,
                             float* __restrict__ losses)
{
    const int bq  = blockIdx.x;
    const int tid = threadIdx.x;   // 128 threads

    __shared__ float cw[128];
    __shared__ int   ag[128];
    __shared__ float tv[NW][128];
    __shared__ float maskf[128];
    __shared__ float lg[8];

    if (tid < HW) {
        float g0 = -INFINITY; int garg = 0;
#pragma unroll
        for (int n = 0; n < NW; ++n) {
            const float4 a = pout[(bq * NPART + n * 2 + 0) * HW + tid];
            const float4 b = pout[(bq * NPART + n * 2 + 1) * HW + tid];
            if (a.x > g0) { g0 = a.x; garg = __float_as_int(a.w); }   // h=0 first (smaller j)
            else if (a.x == g0) { int aa = __float_as_int(a.w); if (aa < garg) garg = aa; }
            if (b.x > g0) { g0 = b.x; garg = __float_as_int(b.w); }
            else if (b.x == g0) { int ba = __float_as_int(b.w); if (ba < garg) garg = ba; }
            // merge top3 of the two halves
            float t0 = a.x, t1 = a.y, t2 = a.z;
            float m1 = fminf(t0, b.x); t0 = fmaxf(t0, b.x);
            float m2 = fminf(t1, m1);  t1 = fmaxf(t1, m1); t2 = fmaxf(t2, m2);
            m1 = fminf(t0, b.y); t0 = fmaxf(t0, b.y);
            m2 = fminf(t1, m1);  t1 = fmaxf(t1, m1); t2 = fmaxf(t2, m2);
            m1 = fminf(t0, b.z); t0 = fmaxf(t0, b.z);
            m2 = fminf(t1, m1);  t1 = fmaxf(t1, m1); t2 = fmaxf(t2, m2);
            tv[n][tid] = (t0 + t1 + t2) * (1.f / 3.f);
        }
        cw[tid] = g0 + 1.0f;   // class_wise_max
        ag[tid] = garg;        // query_nearest (global j)
    }
    __syncthreads();
    if (tid < HW) {
        const float mycw = cw[tid];
        const int   myag = ag[tid];
        float ok = 1.f;
        for (int m2 = 0; m2 < HW; ++m2) {
            if (m2 == tid) continue;
            if (ag[m2] == myag) {
                float c2 = cw[m2];
                if (c2 > mycw || (c2 == mycw && m2 < tid)) ok = 0.f;  // first-max over mq
            }
        }
        maskf[tid] = ok;
    }
    __syncthreads();
    if (tid < NW) {
        float s = 0.f;
        for (int mq = 0; mq < HW; ++mq) s += maskf[mq] * tv[tid][mq];
        lg[tid] = s * 0.5f;   // / TEMPERATURE
    }
    __syncthreads();
    if (tid == 0) {
        float m = lg[0];
#pragma unroll
        for (int n2 = 1; n2 < NW; ++n2) m = fmaxf(m, lg[n2]);
        float se = 0.f;
#pragma unroll
        for (int n2 = 0; n2 < NW; ++n2) se += expf(lg[n2] - m);
        int y = qy[bq];
        losses[bq] = -(lg[y] - m - logf(se));
    }
}

// ---------------------------------------------------------------------------
__global__ void reduce_kernel(const float* __restrict__ losses, float* __restrict__ out) {
    const int tid = threadIdx.x;   // 64 threads
    float s = 0.f;
    for (int i = tid; i < NBQ; i += 64) s += losses[i];
#pragma unroll
    for (int off = 32; off > 0; off >>= 1) s += __shfl_down(s, off);
    if (tid == 0) out[0] = s * (1.f / NBQ);
}

// ---------------------------------------------------------------------------
extern "C" void kernel_launch(void* const* d_in, const int* in_sizes, int n_in,
                              void* d_out, int out_size, void* d_ws, size_t ws_size,
                              hipStream_t stream)
{
    const float* sup = (const float*)d_in[0];   // [4][25][640][121]
    const float* qry = (const float*)d_in[1];   // [4][75][640][121]
    const int*   qy  = (const int*)d_in[3];     // [4][75]
    float* out = (float*)d_out;
    float* ws  = (float*)d_ws;

    __hip_bfloat16* Sbf = (__hip_bfloat16*)(ws + OFF_SBF);
    __hip_bfloat16* Qbf = (__hip_bfloat16*)(ws + OFF_QBF);
    float4* pout  = (float4*)(ws + OFF_P);
    float* losses = ws + OFF_LOSS;

    hipLaunchKernelGGL(prep_kernel, dim3(BB * SS + NBQ), dim3(256), 0, stream,
                       sup, qry, Sbf, Qbf);
    hipLaunchKernelGGL(simi_kernel, dim3(NBQ, NPART), dim3(256), 0, stream,
                       Sbf, Qbf, pout);
    hipLaunchKernelGGL(merge_kernel, dim3(NBQ), dim3(128), 0, stream, pout, qy, losses);
    hipLaunchKernelGGL(reduce_kernel, dim3(1), dim3(64), 0, stream, losses, out);
}

// Round 5
// 481.376 us; speedup vs baseline: 1.0444x; 1.0444x over previous
//
#include <hip/hip_runtime.h>
#include <hip/hip_bf16.h>
#include <math.h>

#define BB 4
#define QQ 75
#define NBQ 300        // BB*QQ
#define CC 640
#define HW 121
#define NW 5
#define KS 5
#define SS 25          // NW*KS
#define MS 605         // KS*HW
#define JT 3025        // NW*MS

typedef __attribute__((ext_vector_type(8))) short short8;
typedef __attribute__((ext_vector_type(4))) float f32x4;

// workspace float offsets
#define OFF_SBF   0
#define SBF_F     (BB*JT*CC/2)            // bf16 storage
#define OFF_QBF   (OFF_SBF + SBF_F)
#define QBF_F     (NBQ*HW*CC/2)
#define OFF_P     (OFF_QBF + QBF_F)       // float4 partials [300][5][121]

__device__ __forceinline__ void async16(const void* g, void* l) {
    __builtin_amdgcn_global_load_lds(
        (const __attribute__((address_space(1))) unsigned int*)g,
        (__attribute__((address_space(3))) unsigned int*)l, 16, 0, 0);
}

// ---------------------------------------------------------------------------
// Fused: norm (pass 1, HBM-stream) + normalize/cast/transpose (pass 2, cache-hot).
// One block per descriptor column. Output [col][hw][c] bf16.
__global__ void prep_kernel(const float* __restrict__ sup, const float* __restrict__ qry,
                            __hip_bfloat16* __restrict__ Sbf, __hip_bfloat16* __restrict__ Qbf)
{
    const int col = blockIdx.x;      // 0..399
    const int t   = threadIdx.x;     // 256
    const float* src;
    __hip_bfloat16* dst;
    if (col < BB * SS) {
        const int b = col / SS, s = col % SS;
        const int n = s / KS, k = s % KS;
        src = sup + (size_t)col * (CC * HW);
        dst = Sbf + ((size_t)b * JT + n * MS + k * HW) * CC;
    } else {
        const int bq = col - BB * SS;
        src = qry + (size_t)bq * (CC * HW);
        dst = Qbf + (size_t)bq * (HW * CC);
    }

    __shared__ float inv[128];
    __shared__ float T[32][128];

    // ---- phase 1: sum of squares per hw (2 c-interleaved partials) ----
    const int cc2 = t >> 7, hw1 = t & 127;
    float ss = 0.f;
    if (hw1 < HW) {
        const float* p = src + hw1;
#pragma unroll 8
        for (int c = cc2; c < CC; c += 2) { float v = p[(size_t)c * HW]; ss = fmaf(v, v, ss); }
    }
    T[cc2][hw1] = ss;
    __syncthreads();
    if (t < 128) inv[t] = (t < HW) ? 1.f / (sqrtf(T[0][t] + T[1][t]) + 1e-8f) : 0.f;

    // ---- phase 2: scale + transpose + bf16 write ----
    for (int c0 = 0; c0 < CC; c0 += 32) {
        __syncthreads();
#pragma unroll
        for (int i = 0; i < 16; ++i) {
            int idx = t + i * 256;
            int cc = idx >> 7, hw = idx & 127;
            if (hw < HW) T[cc][hw] = src[(size_t)(c0 + cc) * HW + hw] * inv[hw];
        }
        __syncthreads();
        const int hw = t >> 1, half = t & 1;
        if (hw < HW) {
            __hip_bfloat16 hv[16];
#pragma unroll
            for (int i = 0; i < 16; ++i) hv[i] = __float2bfloat16(T[half * 16 + i][hw]);
            int4* op = reinterpret_cast<int4*>(dst + (size_t)hw * CC + c0 + half * 16);
            op[0] = reinterpret_cast<int4*>(hv)[0];
            op[1] = reinterpret_cast<int4*>(hv)[1];
        }
    }
}

// ---------------------------------------------------------------------------
// Per (bq, n): MFMA cosine GEMM [121 x 605], register-resident top3/argmax,
// double-buffered LDS pipeline (prefetch issued AFTER the barrier so the DMA
// overlaps the whole compute phase; one barrier per K-chunk).
__launch_bounds__(256, 2)
__global__ void simi_kernel(const __hip_bfloat16* __restrict__ Sbf,
                            const __hip_bfloat16* __restrict__ Qbf,
                            float4* __restrict__ pout)
{
    const int bq  = blockIdx.x;
    const int n   = blockIdx.y;
    const int b   = bq / QQ;
    const int tid = threadIdx.x;
    const int lane = tid & 63, wid = tid >> 6;
    const int l15 = lane & 15, l4 = lane >> 4;
    const int wr0 = (wid & 1) * 64;    // wave row base
    const int wc0 = (wid >> 1) * 64;   // wave col base (tile-local)

    const unsigned short* qbase = (const unsigned short*)(Qbf + (size_t)bq * (HW * CC));
    const unsigned short* sbase = (const unsigned short*)(Sbf + ((size_t)b * JT + n * MS) * CC);

    __shared__ __align__(16) unsigned short AsBuf[2][128 * 64];  // 2 x 16 KB
    __shared__ __align__(16) unsigned short BsBuf[2][128 * 64];  // 2 x 16 KB  (64 KB total)

    const int srow = lane >> 3;              // row within 8-row segment
    const int kb   = (lane & 7) ^ srow;      // swizzled k-block held by this lane
    int aoff[4];
#pragma unroll
    for (int p = 0; p < 4; ++p) {
        int arow = wid * 32 + p * 8 + srow;
        int grow = arow < HW ? arow : HW - 1;
        aoff[p] = grow * CC + kb * 8;
    }
    const int ldso_base = wid * 4096 + lane * 16;

    // stage one (ms0, c0) chunk into buffer nb
#define STAGE(ms0_, c0_, nb_)                                                        \
    {                                                                                \
        _Pragma("unroll")                                                            \
        for (int p = 0; p < 4; ++p) {                                                \
            const int ldso = ldso_base + p * 1024;                                   \
            async16(qbase + aoff[p] + (c0_), (char*)&AsBuf[nb_][0] + ldso);          \
            int j_ = (ms0_) + wid * 32 + p * 8 + srow;                               \
            int jc_ = j_ < MS ? j_ : MS - 1;                                         \
            async16(sbase + jc_ * CC + kb * 8 + (c0_), (char*)&BsBuf[nb_][0] + ldso);\
        }                                                                            \
    }

    float rt0[16], rt1[16], rt2[16]; int ra[16];
#pragma unroll
    for (int i = 0; i < 16; ++i) { rt0[i] = -INFINITY; rt1[i] = -INFINITY; rt2[i] = -INFINITY; ra[i] = 0; }

    // prologue: stage first chunk, drain
    STAGE(0, 0, 0);
    __syncthreads();
    int nb = 0;

    for (int ms0 = 0; ms0 < MS; ms0 += 128) {
        f32x4 acc[4][4];
#pragma unroll
        for (int mi = 0; mi < 4; ++mi)
#pragma unroll
            for (int ni = 0; ni < 4; ++ni)
#pragma unroll
                for (int r = 0; r < 4; ++r) acc[mi][ni][r] = 0.f;

        for (int c0 = 0; c0 < CC; c0 += 64) {
            // prefetch next chunk into the other buffer (issued after the
            // previous barrier -> overlaps this iteration's compute)
            int nc = c0 + 64, nms = ms0;
            if (nc == CC) { nc = 0; nms = ms0 + 128; }
            if (nms < MS) STAGE(nms, nc, nb ^ 1);

            // compute from buffer nb
#pragma unroll
            for (int ks = 0; ks < 2; ++ks) {
                const int slot = (ks * 4 + l4) ^ (l15 & 7);
                short8 af[4], bf[4];
#pragma unroll
                for (int mi = 0; mi < 4; ++mi)
                    af[mi] = *(const short8*)(&AsBuf[nb][0] + (wr0 + mi * 16 + l15) * 64 + slot * 8);
#pragma unroll
                for (int ni = 0; ni < 4; ++ni)
                    bf[ni] = *(const short8*)(&BsBuf[nb][0] + (wc0 + ni * 16 + l15) * 64 + slot * 8);
#pragma unroll
                for (int mi = 0; mi < 4; ++mi)
#pragma unroll
                    for (int ni = 0; ni < 4; ++ni)
                        acc[mi][ni] = __builtin_amdgcn_mfma_f32_16x16x32_bf16(
                            af[mi], bf[ni], acc[mi][ni], 0, 0, 0);
            }
            nb ^= 1;
            __syncthreads();   // drains the prefetch DMA; also fences buffer reuse
        }

        // in-register epilogue: ascending j keeps first-max tie rule
        int jg[4]; bool jvalid[4];
#pragma unroll
        for (int nf = 0; nf < 4; ++nf) {
            const int jl = ms0 + wc0 + nf * 16 + l15;
            jvalid[nf] = (jl < MS);
            jg[nf] = n * MS + jl;
        }
#pragma unroll
        for (int mi = 0; mi < 4; ++mi)
#pragma unroll
            for (int nf = 0; nf < 4; ++nf)
#pragma unroll
                for (int r = 0; r < 4; ++r) {
                    const int si = mi * 4 + r;
                    float v = jvalid[nf] ? acc[mi][nf][r] : -INFINITY;
                    const bool gt = v > rt0[si];
                    ra[si] = gt ? jg[nf] : ra[si];
                    const float m1 = fminf(rt0[si], v);
                    rt0[si] = fmaxf(rt0[si], v);
                    const float m2 = fminf(rt1[si], m1);
                    rt1[si] = fmaxf(rt1[si], m1);
                    rt2[si] = fmaxf(rt2[si], m2);
                }
    }

    // butterfly merge across the 16 lanes of each col-group (masks 1,2,4,8)
#pragma unroll
    for (int si = 0; si < 16; ++si) {
#pragma unroll
        for (int mask = 1; mask <= 8; mask <<= 1) {
            const float o0 = __shfl_xor(rt0[si], mask);
            const float o1 = __shfl_xor(rt1[si], mask);
            const float o2 = __shfl_xor(rt2[si], mask);
            const int   oa = __shfl_xor(ra[si],  mask);
            const bool take = (o0 > rt0[si]) || (o0 == rt0[si] && oa < ra[si]);
            ra[si] = take ? oa : ra[si];
            float m1 = fminf(rt0[si], o0); rt0[si] = fmaxf(rt0[si], o0);
            float m2 = fminf(rt1[si], m1); rt1[si] = fmaxf(rt1[si], m1);
            rt2[si] = fmaxf(rt2[si], m2);
            m1 = fminf(rt0[si], o1); rt0[si] = fmaxf(rt0[si], o1);
            m2 = fminf(rt1[si], m1); rt1[si] = fmaxf(rt1[si], m1);
            rt2[si] = fmaxf(rt2[si], m2);
            m1 = fminf(rt0[si], o2); rt0[si] = fmaxf(rt0[si], o2);
            m2 = fminf(rt1[si], m1); rt1[si] = fmaxf(rt1[si], m1);
            rt2[si] = fmaxf(rt2[si], m2);
        }
    }

    // select this lane's slot (si == l15)
    float s0 = rt0[0], s1 = rt1[0], s2 = rt2[0]; int sa = ra[0];
#pragma unroll
    for (int i = 1; i < 16; ++i) {
        const bool p = (l15 == i);
        s0 = p ? rt0[i] : s0; s1 = p ? rt1[i] : s1; s2 = p ? rt2[i] : s2; sa = p ? ra[i] : sa;
    }
    const int m = wr0 + (l15 >> 2) * 16 + l4 * 4 + (l15 & 3);

    // cross-wave (col-half) merge via LDS overlay on the dead tile buffers
    __syncthreads();                       // all tile reads done -> safe to overlay
    float4* mbuf = (float4*)&AsBuf[0][0];
    if ((wid >> 1) == 0) {
        float4 v; v.x = s0; v.y = s1; v.z = s2; v.w = __int_as_float(sa);
        mbuf[m] = v;
    }
    __syncthreads();
    if ((wid >> 1) == 1) {
        const float4 o = mbuf[m];
        const int oa = __float_as_int(o.w);
        const bool take = (o.x > s0) || (o.x == s0 && oa < sa);
        sa = take ? oa : sa;
        float m1 = fminf(s0, o.x); s0 = fmaxf(s0, o.x);
        float m2 = fminf(s1, m1);  s1 = fmaxf(s1, m1);
        s2 = fmaxf(s2, m2);
        m1 = fminf(s0, o.y); s0 = fmaxf(s0, o.y);
        m2 = fminf(s1, m1);  s1 = fmaxf(s1, m1);
        s2 = fmaxf(s2, m2);
        m1 = fminf(s0, o.z); s0 = fmaxf(s0, o.z);
        m2 = fminf(s1, m1);  s1 = fmaxf(s1, m1);
        s2 = fmaxf(s2, m2);
        if (m < HW) {
            float4 v; v.x = s0; v.y = s1; v.z = s2; v.w = __int_as_float(sa);
            pout[(bq * NW + n) * HW + m] = v;
        }
    }
#undef STAGE
}

// ---------------------------------------------------------------------------
// Merge 5 per-n partials, mutual-NN mask, logits, per-query CE, atomic mean.
__global__ void merge_kernel(const float4* __restrict__ pout, const int* __restrict__ qy,
                             float* __restrict__ out)
{
    const int bq  = blockIdx.x;
    const int tid = threadIdx.x;   // 128 threads

    __shared__ float cw[128];
    __shared__ int   ag[128];
    __shared__ float tv[NW][128];
    __shared__ float maskf[128];
    __shared__ float lg[8];

    if (tid < HW) {
        float g0 = -INFINITY; int garg = 0;
#pragma unroll
        for (int n = 0; n < NW; ++n) {
            const float4 a = pout[(bq * NW + n) * HW + tid];
            if (a.x > g0) { g0 = a.x; garg = __float_as_int(a.w); }   // asc n = asc j
            tv[n][tid] = (a.x + a.y + a.z) * (1.f / 3.f);
        }
        cw[tid] = g0 + 1.0f;   // class_wise_max
        ag[tid] = garg;        // query_nearest (global j)
    }
    __syncthreads();
    if (tid < HW) {
        const float mycw = cw[tid];
        const int   myag = ag[tid];
        float ok = 1.f;
        for (int m2 = 0; m2 < HW; ++m2) {
            if (m2 == tid) continue;
            if (ag[m2] == myag) {
                float c2 = cw[m2];
                if (c2 > mycw || (c2 == mycw && m2 < tid)) ok = 0.f;  // first-max over mq
            }
        }
        maskf[tid] = ok;
    }
    __syncthreads();
    if (tid < NW) {
        float s = 0.f;
        for (int mq = 0; mq < HW; ++mq) s += maskf[mq] * tv[tid][mq];
        lg[tid] = s * 0.5f;   // / TEMPERATURE
    }
    __syncthreads();
    if (tid == 0) {
        float m = lg[0];
#pragma unroll
        for (int n2 = 1; n2 < NW; ++n2) m = fmaxf(m, lg[n2]);
        float se = 0.f;
#pragma unroll
        for (int n2 = 0; n2 < NW; ++n2) se += expf(lg[n2] - m);
        int y = qy[bq];
        atomicAdd(out, -(lg[y] - m - logf(se)) * (1.f / NBQ));
    }
}

// ---------------------------------------------------------------------------
extern "C" void kernel_launch(void* const* d_in, const int* in_sizes, int n_in,
                              void* d_out, int out_size, void* d_ws, size_t ws_size,
                              hipStream_t stream)
{
    const float* sup = (const float*)d_in[0];   // [4][25][640][121]
    const float* qry = (const float*)d_in[1];   // [4][75][640][121]
    const int*   qy  = (const int*)d_in[3];     // [4][75]
    float* out = (float*)d_out;
    float* ws  = (float*)d_ws;

    __hip_bfloat16* Sbf = (__hip_bfloat16*)(ws + OFF_SBF);
    __hip_bfloat16* Qbf = (__hip_bfloat16*)(ws + OFF_QBF);
    float4* pout = (float4*)(ws + OFF_P);

    hipMemsetAsync(out, 0, sizeof(float), stream);
    hipLaunchKernelGGL(prep_kernel, dim3(BB * SS + NBQ), dim3(256), 0, stream,
                       sup, qry, Sbf, Qbf);
    hipLaunchKernelGGL(simi_kernel, dim3(NBQ, NW), dim3(256), 0, stream,
                       Sbf, Qbf, pout);
    hipLaunchKernelGGL(merge_kernel, dim3(NBQ), dim3(128), 0, stream, pout, qy, out);
}

// Round 6
// 454.166 us; speedup vs baseline: 1.1070x; 1.0599x over previous
//
#include <hip/hip_runtime.h>
#include <hip/hip_bf16.h>
#include <math.h>

#define BB 4
#define QQ 75
#define NBQ 300        // BB*QQ
#define CC 640
#define HW 121
#define NW 5
#define KS 5
#define SS 25          // NW*KS
#define MS 605         // KS*HW
#define JT 3025        // NW*MS
#define BQ_PER_XCD 38  // ceil(300/8)

typedef __attribute__((ext_vector_type(8))) short short8;
typedef __attribute__((ext_vector_type(4))) float f32x4;

// workspace float offsets
#define OFF_SBF   0
#define SBF_F     (BB*JT*CC/2)            // bf16 storage
#define OFF_QBF   (OFF_SBF + SBF_F)
#define QBF_F     (NBQ*HW*CC/2)
#define OFF_P     (OFF_QBF + QBF_F)       // float4 partials [300][5][121]

__device__ __forceinline__ void async16(const void* g, void* l) {
    __builtin_amdgcn_global_load_lds(
        (const __attribute__((address_space(1))) unsigned int*)g,
        (__attribute__((address_space(3))) unsigned int*)l, 16, 0, 0);
}

// ---------------------------------------------------------------------------
// Fused: norm (pass 1, HBM-stream, 16 outstanding loads/thread) +
// normalize/cast/transpose (pass 2, cache-hot). One block per descriptor
// column. Output [col][hw][c] bf16. Block 0 also zeroes d_out.
__global__ void prep_kernel(const float* __restrict__ sup, const float* __restrict__ qry,
                            __hip_bfloat16* __restrict__ Sbf, __hip_bfloat16* __restrict__ Qbf,
                            float* __restrict__ out)
{
    const int col = blockIdx.x;      // 0..399
    const int t   = threadIdx.x;     // 256
    if (col == 0 && t == 0) out[0] = 0.f;   // replaces memset dispatch
    const float* src;
    __hip_bfloat16* dst;
    if (col < BB * SS) {
        const int b = col / SS, s = col % SS;
        const int n = s / KS, k = s % KS;
        src = sup + (size_t)col * (CC * HW);
        dst = Sbf + ((size_t)b * JT + n * MS + k * HW) * CC;
    } else {
        const int bq = col - BB * SS;
        src = qry + (size_t)bq * (CC * HW);
        dst = Qbf + (size_t)bq * (HW * CC);
    }

    __shared__ float inv[128];
    __shared__ float T[32][128];

    // ---- phase 1: sum of squares per hw (2 c-interleaved threads, 2 accs) ----
    const int cc2 = t >> 7, hw1 = t & 127;
    float ss0 = 0.f, ss1 = 0.f;
    if (hw1 < HW) {
        const float* p = src + hw1;
#pragma unroll 16
        for (int c = cc2; c < CC; c += 4) {
            float v0 = p[(size_t)c * HW];
            float v1 = p[(size_t)(c + 2) * HW];
            ss0 = fmaf(v0, v0, ss0);
            ss1 = fmaf(v1, v1, ss1);
        }
    }
    T[cc2][hw1] = ss0 + ss1;
    __syncthreads();
    if (t < 128) inv[t] = (t < HW) ? 1.f / (sqrtf(T[0][t] + T[1][t]) + 1e-8f) : 0.f;

    // ---- phase 2: scale + transpose + bf16 write ----
    for (int c0 = 0; c0 < CC; c0 += 32) {
        __syncthreads();
#pragma unroll
        for (int i = 0; i < 16; ++i) {
            int idx = t + i * 256;
            int cc = idx >> 7, hw = idx & 127;
            if (hw < HW) T[cc][hw] = src[(size_t)(c0 + cc) * HW + hw] * inv[hw];
        }
        __syncthreads();
        const int hw = t >> 1, half = t & 1;
        if (hw < HW) {
            __hip_bfloat16 hv[16];
#pragma unroll
            for (int i = 0; i < 16; ++i) hv[i] = __float2bfloat16(T[half * 16 + i][hw]);
            int4* op = reinterpret_cast<int4*>(dst + (size_t)hw * CC + c0 + half * 16);
            op[0] = reinterpret_cast<int4*>(hv)[0];
            op[1] = reinterpret_cast<int4*>(hv)[1];
        }
    }
}

// ---------------------------------------------------------------------------
// Per (bq, n): MFMA cosine GEMM [121 x 605], register-resident top3/argmax,
// double-buffered LDS pipeline. XCD-aware swizzle: blockIdx&7 -> XCD,
// contiguous bq range per XCD, n innermost (A consumed 5x back-to-back,
// B panels of one b stay L2-hot).
__launch_bounds__(256, 2)
__global__ void simi_kernel(const __hip_bfloat16* __restrict__ Sbf,
                            const __hip_bfloat16* __restrict__ Qbf,
                            float4* __restrict__ pout)
{
    const int xcd   = blockIdx.x & 7;
    const int local = blockIdx.x >> 3;      // 0..189
    const int n     = local % NW;
    const int bq    = xcd * BQ_PER_XCD + local / NW;
    if (bq >= NBQ) return;
    const int b   = bq / QQ;
    const int tid = threadIdx.x;
    const int lane = tid & 63, wid = tid >> 6;
    const int l15 = lane & 15, l4 = lane >> 4;
    const int wr0 = (wid & 1) * 64;    // wave row base
    const int wc0 = (wid >> 1) * 64;   // wave col base (tile-local)

    const unsigned short* qbase = (const unsigned short*)(Qbf + (size_t)bq * (HW * CC));
    const unsigned short* sbase = (const unsigned short*)(Sbf + ((size_t)b * JT + n * MS) * CC);

    __shared__ __align__(16) unsigned short AsBuf[2][128 * 64];  // 2 x 16 KB
    __shared__ __align__(16) unsigned short BsBuf[2][128 * 64];  // 2 x 16 KB  (64 KB total)

    const int srow = lane >> 3;              // row within 8-row segment
    const int kb   = (lane & 7) ^ srow;      // swizzled k-block held by this lane
    int aoff[4];
#pragma unroll
    for (int p = 0; p < 4; ++p) {
        int arow = wid * 32 + p * 8 + srow;
        int grow = arow < HW ? arow : HW - 1;
        aoff[p] = grow * CC + kb * 8;
    }
    const int ldso_base = wid * 4096 + lane * 16;

    // stage one (ms0, c0) chunk into buffer nb
#define STAGE(ms0_, c0_, nb_)                                                        \
    {                                                                                \
        _Pragma("unroll")                                                            \
        for (int p = 0; p < 4; ++p) {                                                \
            const int ldso = ldso_base + p * 1024;                                   \
            async16(qbase + aoff[p] + (c0_), (char*)&AsBuf[nb_][0] + ldso);          \
            int j_ = (ms0_) + wid * 32 + p * 8 + srow;                               \
            int jc_ = j_ < MS ? j_ : MS - 1;                                         \
            async16(sbase + jc_ * CC + kb * 8 + (c0_), (char*)&BsBuf[nb_][0] + ldso);\
        }                                                                            \
    }

    float rt0[16], rt1[16], rt2[16]; int ra[16];
#pragma unroll
    for (int i = 0; i < 16; ++i) { rt0[i] = -INFINITY; rt1[i] = -INFINITY; rt2[i] = -INFINITY; ra[i] = 0; }

    // prologue: stage first chunk, drain
    STAGE(0, 0, 0);
    __syncthreads();
    int nb = 0;

    for (int ms0 = 0; ms0 < MS; ms0 += 128) {
        f32x4 acc[4][4];
#pragma unroll
        for (int mi = 0; mi < 4; ++mi)
#pragma unroll
            for (int ni = 0; ni < 4; ++ni)
#pragma unroll
                for (int r = 0; r < 4; ++r) acc[mi][ni][r] = 0.f;

        for (int c0 = 0; c0 < CC; c0 += 64) {
            // prefetch next chunk into the other buffer (issued after the
            // previous barrier -> overlaps this iteration's compute)
            int nc = c0 + 64, nms = ms0;
            if (nc == CC) { nc = 0; nms = ms0 + 128; }
            if (nms < MS) STAGE(nms, nc, nb ^ 1);

            // compute from buffer nb
#pragma unroll
            for (int ks = 0; ks < 2; ++ks) {
                const int slot = (ks * 4 + l4) ^ (l15 & 7);
                short8 af[4], bf[4];
#pragma unroll
                for (int mi = 0; mi < 4; ++mi)
                    af[mi] = *(const short8*)(&AsBuf[nb][0] + (wr0 + mi * 16 + l15) * 64 + slot * 8);
#pragma unroll
                for (int ni = 0; ni < 4; ++ni)
                    bf[ni] = *(const short8*)(&BsBuf[nb][0] + (wc0 + ni * 16 + l15) * 64 + slot * 8);
#pragma unroll
                for (int mi = 0; mi < 4; ++mi)
#pragma unroll
                    for (int ni = 0; ni < 4; ++ni)
                        acc[mi][ni] = __builtin_amdgcn_mfma_f32_16x16x32_bf16(
                            af[mi], bf[ni], acc[mi][ni], 0, 0, 0);
            }
            nb ^= 1;
            __syncthreads();   // drains the prefetch DMA; also fences buffer reuse
        }

        // in-register epilogue: ascending j keeps first-max tie rule
        int jg[4]; bool jvalid[4];
#pragma unroll
        for (int nf = 0; nf < 4; ++nf) {
            const int jl = ms0 + wc0 + nf * 16 + l15;
            jvalid[nf] = (jl < MS);
            jg[nf] = n * MS + jl;
        }
#pragma unroll
        for (int mi = 0; mi < 4; ++mi)
#pragma unroll
            for (int nf = 0; nf < 4; ++nf)
#pragma unroll
                for (int r = 0; r < 4; ++r) {
                    const int si = mi * 4 + r;
                    float v = jvalid[nf] ? acc[mi][nf][r] : -INFINITY;
                    const bool gt = v > rt0[si];
                    ra[si] = gt ? jg[nf] : ra[si];
                    const float m1 = fminf(rt0[si], v);
                    rt0[si] = fmaxf(rt0[si], v);
                    const float m2 = fminf(rt1[si], m1);
                    rt1[si] = fmaxf(rt1[si], m1);
                    rt2[si] = fmaxf(rt2[si], m2);
                }
    }

    // butterfly merge across the 16 lanes of each col-group (masks 1,2,4,8)
#pragma unroll
    for (int si = 0; si < 16; ++si) {
#pragma unroll
        for (int mask = 1; mask <= 8; mask <<= 1) {
            const float o0 = __shfl_xor(rt0[si], mask);
            const float o1 = __shfl_xor(rt1[si], mask);
            const float o2 = __shfl_xor(rt2[si], mask);
            const int   oa = __shfl_xor(ra[si],  mask);
            const bool take = (o0 > rt0[si]) || (o0 == rt0[si] && oa < ra[si]);
            ra[si] = take ? oa : ra[si];
            float m1 = fminf(rt0[si], o0); rt0[si] = fmaxf(rt0[si], o0);
            float m2 = fminf(rt1[si], m1); rt1[si] = fmaxf(rt1[si], m1);
            rt2[si] = fmaxf(rt2[si], m2);
            m1 = fminf(rt0[si], o1); rt0[si] = fmaxf(rt0[si], o1);
            m2 = fminf(rt1[si], m1); rt1[si] = fmaxf(rt1[si], m1);
            rt2[si] = fmaxf(rt2[si], m2);
            m1 = fminf(rt0[si], o2); rt0[si] = fmaxf(rt0[si], o2);
            m2 = fminf(rt1[si], m1); rt1[si] = fmaxf(rt1[si], m1);
            rt2[si] = fmaxf(rt2[si], m2);
        }
    }

    // select this lane's slot (si == l15)
    float s0 = rt0[0], s1 = rt1[0], s2 = rt2[0]; int sa = ra[0];
#pragma unroll
    for (int i = 1; i < 16; ++i) {
        const bool p = (l15 == i);
        s0 = p ? rt0[i] : s0; s1 = p ? rt1[i] : s1; s2 = p ? rt2[i] : s2; sa = p ? ra[i] : sa;
    }
    const int m = wr0 + (l15 >> 2) * 16 + l4 * 4 + (l15 & 3);

    // cross-wave (col-half) merge via LDS overlay on the dead tile buffers
    __syncthreads();                       // all tile reads done -> safe to overlay
    float4* mbuf = (float4*)&AsBuf[0][0];
    if ((wid >> 1) == 0) {
        float4 v; v.x = s0; v.y = s1; v.z = s2; v.w = __int_as_float(sa);
        mbuf[m] = v;
    }
    __syncthreads();
    if ((wid >> 1) == 1) {
        const float4 o = mbuf[m];
        const int oa = __float_as_int(o.w);
        const bool take = (o.x > s0) || (o.x == s0 && oa < sa);
        sa = take ? oa : sa;
        float m1 = fminf(s0, o.x); s0 = fmaxf(s0, o.x);
        float m2 = fminf(s1, m1);  s1 = fmaxf(s1, m1);
        s2 = fmaxf(s2, m2);
        m1 = fminf(s0, o.y); s0 = fmaxf(s0, o.y);
        m2 = fminf(s1, m1);  s1 = fmaxf(s1, m1);
        s2 = fmaxf(s2, m2);
        m1 = fminf(s0, o.z); s0 = fmaxf(s0, o.z);
        m2 = fminf(s1, m1);  s1 = fmaxf(s1, m1);
        s2 = fmaxf(s2, m2);
        if (m < HW) {
            float4 v; v.x = s0; v.y = s1; v.z = s2; v.w = __int_as_float(sa);
            pout[(bq * NW + n) * HW + m] = v;
        }
    }
#undef STAGE
}

// ---------------------------------------------------------------------------
// Merge 5 per-n partials, mutual-NN mask, logits, per-query CE, atomic mean.
__global__ void merge_kernel(const float4* __restrict__ pout, const int* __restrict__ qy,
                             float* __restrict__ out)
{
    const int bq  = blockIdx.x;
    const int tid = threadIdx.x;   // 128 threads

    __shared__ float cw[128];
    __shared__ int   ag[128];
    __shared__ float tv[NW][128];
    __shared__ float maskf[128];
    __shared__ float lg[8];

    if (tid < HW) {
        float g0 = -INFINITY; int garg = 0;
#pragma unroll
        for (int n = 0; n < NW; ++n) {
            const float4 a = pout[(bq * NW + n) * HW + tid];
            if (a.x > g0) { g0 = a.x; garg = __float_as_int(a.w); }   // asc n = asc j
            tv[n][tid] = (a.x + a.y + a.z) * (1.f / 3.f);
        }
        cw[tid] = g0 + 1.0f;   // class_wise_max
        ag[tid] = garg;        // query_nearest (global j)
    }
    __syncthreads();
    if (tid < HW) {
        const float mycw = cw[tid];
        const int   myag = ag[tid];
        float ok = 1.f;
        for (int m2 = 0; m2 < HW; ++m2) {
            if (m2 == tid) continue;
            if (ag[m2] == myag) {
                float c2 = cw[m2];
                if (c2 > mycw || (c2 == mycw && m2 < tid)) ok = 0.f;  // first-max over mq
            }
        }
        maskf[tid] = ok;
    }
    __syncthreads();
    if (tid < NW) {
        float s = 0.f;
        for (int mq = 0; mq < HW; ++mq) s += maskf[mq] * tv[tid][mq];
        lg[tid] = s * 0.5f;   // / TEMPERATURE
    }
    __syncthreads();
    if (tid == 0) {
        float m = lg[0];
#pragma unroll
        for (int n2 = 1; n2 < NW; ++n2) m = fmaxf(m, lg[n2]);
        float se = 0.f;
#pragma unroll
        for (int n2 = 0; n2 < NW; ++n2) se += expf(lg[n2] - m);
        int y = qy[bq];
        atomicAdd(out, -(lg[y] - m - logf(se)) * (1.f / NBQ));
    }
}

// ---------------------------------------------------------------------------
extern "C" void kernel_launch(void* const* d_in, const int* in_sizes, int n_in,
                              void* d_out, int out_size, void* d_ws, size_t ws_size,
                              hipStream_t stream)
{
    const float* sup = (const float*)d_in[0];   // [4][25][640][121]
    const float* qry = (const float*)d_in[1];   // [4][75][640][121]
    const int*   qy  = (const int*)d_in[3];     // [4][75]
    float* out = (float*)d_out;
    float* ws  = (float*)d_ws;

    __hip_bfloat16* Sbf = (__hip_bfloat16*)(ws + OFF_SBF);
    __hip_bfloat16* Qbf = (__hip_bfloat16*)(ws + OFF_QBF);
    float4* pout = (float4*)(ws + OFF_P);

    hipLaunchKernelGGL(prep_kernel, dim3(BB * SS + NBQ), dim3(256), 0, stream,
                       sup, qry, Sbf, Qbf, out);
    hipLaunchKernelGGL(simi_kernel, dim3(8 * BQ_PER_XCD * NW), dim3(256), 0, stream,
                       Sbf, Qbf, pout);
    hipLaunchKernelGGL(merge_kernel, dim3(NBQ), dim3(128), 0, stream, pout, qy, out);
}